// Round 6
// baseline (760.790 us; speedup 1.0000x reference)
//
#include <hip/hip_runtime.h>
#include <math.h>

#define EPS_BN 1e-5f

// Problem constants: B=32, NS=200, NQ=100, C=8, L=512, H=32, F=128, N_WAY=20
#define NSUP   6400
#define NQRY   3200
#define NSAMP  9600
#define NWAY   20
#define NSHOTB 200
#define NQB    100

using short8  = __attribute__((ext_vector_type(8))) short;
using floatx4 = __attribute__((ext_vector_type(4))) float;
using f32x2   = __attribute__((ext_vector_type(2))) float;

// split x into hi/lo bf16 (RNE both): x ~= h + l, |err| ~ 2^-17 |x|
__device__ __forceinline__ void bf16_split(float x, unsigned& uh, unsigned& ul) {
    unsigned u = __float_as_uint(x);
    uh = (u + 0x7FFFu + ((u >> 16) & 1u)) >> 16;
    float hf = __uint_as_float(uh << 16);
    float e  = x - hf;
    unsigned ue = __float_as_uint(e);
    ul = (ue + 0x7FFFu + ((ue >> 16) & 1u)) >> 16;
}

// ===========================================================================
// prep (fused): W2 fp32 [64][32][3] and W3 fp32 [128][64][3] -> B-fragment
// order, split hi/lo bf16. Layouts identical to rounds 4/5 (verified):
//  W2: frag=(t*4+nt)*2+hl;           co=nt*16+(lane&15), ci=(lane>>4)*8+j
//  W3: frag=((t*2+ks)*8+nt)*2+hl;    co=nt*16+(lane&15), ci=ks*32+(lane>>4)*8+j
// ===========================================================================
__global__ __launch_bounds__(256) void prep_weights(
    const float* __restrict__ w2, const float* __restrict__ w3,
    unsigned short* __restrict__ Wf2, unsigned short* __restrict__ Wf3)
{
    int b = blockIdx.x;
    if (b < 24) {                         // W2: 24 frags x 512
        int e = b * 512 + threadIdx.x;
        #pragma unroll
        for (int r = 0; r < 2; ++r, e += 256) {
            int frag = e >> 9, off = e & 511;
            int lane = off >> 3, j = off & 7;
            int hl = frag & 1, f2 = frag >> 1;
            int nt = f2 & 3, t = f2 >> 2;
            int co = nt * 16 + (lane & 15);
            int ci = (lane >> 4) * 8 + j;
            float x = w2[(co * 32 + ci) * 3 + t];
            unsigned uh, ul; bf16_split(x, uh, ul);
            Wf2[e] = (unsigned short)(hl ? ul : uh);
        }
    } else {                              // W3: 96 frags x 512
        int e = (b - 24) * 512 + threadIdx.x;
        #pragma unroll
        for (int r = 0; r < 2; ++r, e += 256) {
            int frag = e >> 9, off = e & 511;
            int lane = off >> 3, j = off & 7;
            int hl = frag & 1, f2 = frag >> 1;
            int nt = f2 & 7, f3 = f2 >> 3;
            int ks = f3 & 1, t = f3 >> 1;
            int co = nt * 16 + (lane & 15);
            int ci = ks * 32 + (lane >> 4) * 8 + j;
            float x = w3[(co * 64 + ci) * 3 + t];
            unsigned uh, ul; bf16_split(x, uh, ul);
            Wf3[e] = (unsigned short)(hl ? ul : uh);
        }
    }
}

// ===========================================================================
// Fused encoder. Round-5 structure with:
//  - wave-owns-m-rows decomposition (A-fragments read 1x/2x instead of 4x)
//  - 3-term split-bf16 MFMA (AhWh + AhWl + AlWh)
//  - conv1 on f32x2 packed accumulators (v_pk_fma_f32)
// ===========================================================================
__global__ __launch_bounds__(256, 3) void encoder_fused(
    const float* __restrict__ s_img, const float* __restrict__ q_img,
    const float* __restrict__ pw1, const float* __restrict__ pb1,
    const float* __restrict__ pg1, const float* __restrict__ pbe1,
    const float* __restrict__ pm1, const float* __restrict__ pv1,
    const float* __restrict__ pb2, const float* __restrict__ pg2,
    const float* __restrict__ pbe2, const float* __restrict__ pm2,
    const float* __restrict__ pv2, const unsigned short* __restrict__ Wf2,
    const float* __restrict__ pb3, const float* __restrict__ pg3,
    const float* __restrict__ pbe3, const float* __restrict__ pm3,
    const float* __restrict__ pv3, const unsigned short* __restrict__ Wf3,
    const float* __restrict__ pwf, const float* __restrict__ pbf,
    const float* __restrict__ pgf, const float* __restrict__ pbef,
    const float* __restrict__ pmf, const float* __restrict__ pvf,
    float* __restrict__ feat_out)
{
    // Union region, time-multiplexed:
    //   phase 1: I   = fp32 8 x 514 (16448 B)
    //   phase 2: B1h/B1l = bf16, 258 rows x 40 shorts
    //   phase 3: X2h/X2l = bf16, 130 rows x 72 shorts
    __shared__ __align__(16) char U[41280];
    float* const I   = (float*)U;
    short* const B1h = (short*)U;
    short* const B1l = (short*)(U + 20640);
    short* const X2h = (short*)U;
    short* const X2l = (short*)(U + 18720);
    __shared__ float sc1[32], sh1[32], sc2[64], sh2[64], sc3[128], sh3[128];
    __shared__ float part[2][128];
    __shared__ float featm[128], featr[128];

    const int tid  = threadIdx.x;
    const int sid  = blockIdx.x;
    const int lane = tid & 63;
    const int wid  = tid >> 6;
    const int mrow = lane & 15;
    const int quad = lane >> 4;
    const int kq   = quad * 8;

    const float* xin = (sid < NSUP) ? (s_img + (size_t)sid * 4096)
                                    : (q_img + (size_t)(sid - NSUP) * 4096);

    // ---- fold BN params ----
    if (tid < 32) {
        float s = pg1[tid] * rsqrtf(pv1[tid] + EPS_BN);
        sc1[tid] = s; sh1[tid] = (pb1[tid] - pm1[tid]) * s + pbe1[tid];
    } else if (tid < 96) {
        int c = tid - 32;
        float s = pg2[c] * rsqrtf(pv2[c] + EPS_BN);
        sc2[c] = s; sh2[c] = (pb2[c] - pm2[c]) * s + pbe2[c];
    } else if (tid < 224) {
        int c = tid - 96;
        float s = pg3[c] * rsqrtf(pv3[c] + EPS_BN);
        sc3[c] = s; sh3[c] = (pb3[c] - pm3[c]) * s + pbe3[c];
    }

    // ---- phase 1: stage input ----
    if (tid < 8) { I[tid*514] = 0.f; I[tid*514 + 513] = 0.f; }
    #pragma unroll
    for (int k = 0; k < 4; ++k) {
        int p = k*256 + tid;
        float4 v = ((const float4*)xin)[p];
        int fi = p * 4;
        int ci = fi >> 9;
        int l  = fi & 511;
        float* dst = &I[ci*514 + 1 + l];
        dst[0] = v.x; dst[1] = v.y; dst[2] = v.z; dst[3] = v.w;
    }
    __syncthreads();

    // ---- conv1 (packed fp32: pool-left/right pairs share weights) ----
    float p1[32];
    {
        const int lp = tid;
        f32x2 a[32];
        #pragma unroll
        for (int c = 0; c < 32; ++c) a[c] = (f32x2){0.f, 0.f};
        #pragma unroll
        for (int ci = 0; ci < 8; ++ci) {
            const float x0 = I[ci*514 + 2*lp + 0];
            const float x1 = I[ci*514 + 2*lp + 1];
            const float x2 = I[ci*514 + 2*lp + 2];
            const float x3 = I[ci*514 + 2*lp + 3];
            const f32x2 X0 = {x0, x1}, X1 = {x1, x2}, X2v = {x2, x3};
            #pragma unroll
            for (int co = 0; co < 32; ++co) {
                const float W0 = pw1[(co*8 + ci)*3 + 0];
                const float W1 = pw1[(co*8 + ci)*3 + 1];
                const float W2 = pw1[(co*8 + ci)*3 + 2];
                a[co] += W0*X0 + W1*X1 + W2*X2v;
            }
        }
        #pragma unroll
        for (int co = 0; co < 32; ++co) {
            float v = fmaxf(a[co][0]*sc1[co] + sh1[co], a[co][1]*sc1[co] + sh1[co]);
            p1[co] = fmaxf(v, 0.f);
        }
    }
    __syncthreads();   // I dead

    // ---- phase 2: write B1 (split bf16, conv2 A-layout) ----
    {
        const int row = tid + 1;   // rows 1..256; halos 0, 257
        #pragma unroll
        for (int g = 0; g < 4; ++g) {
            short8 vh, vl;
            #pragma unroll
            for (int j = 0; j < 8; ++j) {
                unsigned uh, ul;
                bf16_split(p1[g*8 + j], uh, ul);
                vh[j] = (short)uh; vl[j] = (short)ul;
            }
            *(short8*)&B1h[row*40 + g*8] = vh;
            *(short8*)&B1l[row*40 + g*8] = vl;
        }
        if (tid < 40) {
            B1h[tid] = 0; B1l[tid] = 0;
            B1h[257*40 + tid] = 0; B1l[257*40 + tid] = 0;
        }
    }
    __syncthreads();

    // ---- conv2 MFMA: M=256, N=64, K=32, 3 taps.
    // Wave w owns mt {4w..4w+3} x ALL nt {0..3}; A read once per (mt,t).
    floatx4 acc2[4][4] = {};   // [mi][nt]
    for (int t = 0; t < 3; ++t) {
        short8 W2h[4], W2l[4];
        #pragma unroll
        for (int nt = 0; nt < 4; ++nt) {
            W2h[nt] = *(const short8*)(Wf2 + (((t*4 + nt)*2 + 0)*512 + lane*8));
            W2l[nt] = *(const short8*)(Wf2 + (((t*4 + nt)*2 + 1)*512 + lane*8));
        }
        #pragma unroll
        for (int mi = 0; mi < 4; ++mi) {
            const int mt = wid*4 + mi;
            const int base = (mt*16 + mrow + t)*40 + kq;
            const short8 Ah = *(const short8*)&B1h[base];
            const short8 Al = *(const short8*)&B1l[base];
            #pragma unroll
            for (int nt = 0; nt < 4; ++nt) {
                acc2[mi][nt] = __builtin_amdgcn_mfma_f32_16x16x32_bf16(Ah, W2h[nt], acc2[mi][nt], 0, 0, 0);
                acc2[mi][nt] = __builtin_amdgcn_mfma_f32_16x16x32_bf16(Ah, W2l[nt], acc2[mi][nt], 0, 0, 0);
                acc2[mi][nt] = __builtin_amdgcn_mfma_f32_16x16x32_bf16(Al, W2h[nt], acc2[mi][nt], 0, 0, 0);
            }
        }
    }
    __syncthreads();   // B1 dead

    // ---- phase 3: conv2 epilogue -> X2 (BN+ReLU+pool2, split bf16) ----
    {
        #pragma unroll
        for (int mi = 0; mi < 4; ++mi) {
            const int mt = wid*4 + mi;
            const int r0 = mt*8 + quad*2 + 1;   // pooled rows (+1 halo)
            #pragma unroll
            for (int nt = 0; nt < 4; ++nt) {
                const int co = nt*16 + mrow;
                const float sc = sc2[co], sh = sh2[co];
                floatx4 d = acc2[mi][nt];
                float v0 = fmaxf(0.f, fmaxf(d[0]*sc + sh, d[1]*sc + sh));
                float v1 = fmaxf(0.f, fmaxf(d[2]*sc + sh, d[3]*sc + sh));
                unsigned uh, ul;
                bf16_split(v0, uh, ul);
                X2h[r0*72 + co] = (short)uh; X2l[r0*72 + co] = (short)ul;
                bf16_split(v1, uh, ul);
                X2h[(r0+1)*72 + co] = (short)uh; X2l[(r0+1)*72 + co] = (short)ul;
            }
        }
        if (tid < 72) {
            X2h[tid] = 0; X2l[tid] = 0;
            X2h[129*72 + tid] = 0; X2l[129*72 + tid] = 0;
        }
    }
    __syncthreads();

    // ---- conv3 MFMA: M=128, N=128, K=64 (2 ks), 3 taps.
    // Wave w: mt {(w&1)*4 ..+3} x nt {(w>>1)*4 ..+3}; A read by 2 waves only.
    floatx4 acc3[4][4] = {};   // [mi][n]
    const int mt0 = (wid & 1) * 4;
    const int ntb = (wid >> 1) * 4;
    for (int t = 0; t < 3; ++t) {
        for (int ks = 0; ks < 2; ++ks) {
            const int fb = (t*2 + ks) * 8;
            short8 W3h[4], W3l[4];
            #pragma unroll
            for (int n = 0; n < 4; ++n) {
                W3h[n] = *(const short8*)(Wf3 + (((fb + ntb + n)*2 + 0)*512 + lane*8));
                W3l[n] = *(const short8*)(Wf3 + (((fb + ntb + n)*2 + 1)*512 + lane*8));
            }
            #pragma unroll
            for (int mi = 0; mi < 4; ++mi) {
                const int base = ((mt0 + mi)*16 + mrow + t)*72 + ks*32 + kq;
                const short8 Ah = *(const short8*)&X2h[base];
                const short8 Al = *(const short8*)&X2l[base];
                #pragma unroll
                for (int n = 0; n < 4; ++n) {
                    acc3[mi][n] = __builtin_amdgcn_mfma_f32_16x16x32_bf16(Ah, W3h[n], acc3[mi][n], 0, 0, 0);
                    acc3[mi][n] = __builtin_amdgcn_mfma_f32_16x16x32_bf16(Ah, W3l[n], acc3[mi][n], 0, 0, 0);
                    acc3[mi][n] = __builtin_amdgcn_mfma_f32_16x16x32_bf16(Al, W3h[n], acc3[mi][n], 0, 0, 0);
                }
            }
        }
    }

    // ---- conv3 epilogue: BN+ReLU+pool2+mean from C-fragments,
    //      2-wave partial reduction (waves sharing an nt-half) ----
    {
        float s[4] = {0.f, 0.f, 0.f, 0.f};
        #pragma unroll
        for (int n = 0; n < 4; ++n) {
            const int co = (ntb + n)*16 + mrow;
            const float sc = sc3[co], sh = sh3[co];
            #pragma unroll
            for (int mi = 0; mi < 4; ++mi) {
                floatx4 d = acc3[mi][n];
                s[n] += fmaxf(0.f, fmaxf(d[0]*sc + sh, d[1]*sc + sh));
                s[n] += fmaxf(0.f, fmaxf(d[2]*sc + sh, d[3]*sc + sh));
            }
        }
        #pragma unroll
        for (int n = 0; n < 4; ++n) {
            s[n] += __shfl_xor(s[n], 16);
            s[n] += __shfl_xor(s[n], 32);
        }
        if (lane < 16) {
            #pragma unroll
            for (int n = 0; n < 4; ++n)
                part[wid & 1][(ntb + n)*16 + lane] = s[n];
        }
    }
    __syncthreads();
    if (tid < 128) featm[tid] = (part[0][tid] + part[1][tid]) * (1.0f / 64.0f);
    __syncthreads();

    // ---- linear 128->128 + BN + ReLU ----
    if (tid < 128) {
        const float* wr = pwf + (size_t)tid * 128;
        float s = 0.f;
        #pragma unroll 4
        for (int i = 0; i < 128; i += 4) {
            float4 w4 = *(const float4*)(wr + i);
            s += w4.x*featm[i] + w4.y*featm[i+1] + w4.z*featm[i+2] + w4.w*featm[i+3];
        }
        s += pbf[tid];
        s = (s - pmf[tid]) * (pgf[tid] * rsqrtf(pvf[tid] + EPS_BN)) + pbef[tid];
        featr[tid] = fmaxf(s, 0.f);
    }
    __syncthreads();

    // ---- L2 normalize ----
    if (tid < 128) {
        float ss = 0.f;
        for (int i = 0; i < 128; ++i) ss += featr[i] * featr[i];
        float n = fmaxf(sqrtf(ss), 1e-12f);
        feat_out[(size_t)sid * 128 + tid] = featr[tid] / n;
    }
}

// ---------------------------------------------------------------------------
__global__ __launch_bounds__(128) void proto_kernel(
    const float* __restrict__ feat_s, const int* __restrict__ s_lab,
    float* __restrict__ protos)
{
    const int b = blockIdx.x / NWAY;
    const int w = blockIdx.x % NWAY;
    const int f = threadIdx.x;
    const float* sf = feat_s + (size_t)b * NSHOTB * 128;
    const int* lab = s_lab + b * NSHOTB;
    float acc = 0.f;
    int cnt = 0;
    for (int s = 0; s < NSHOTB; ++s) {
        int lv = lab[s];
        if (lv == w) { acc += sf[s*128 + f]; cnt++; }
    }
    protos[(size_t)blockIdx.x * 128 + f] = acc / (float)cnt;
}

__global__ __launch_bounds__(256) void dist_kernel(
    const float* __restrict__ feat_q, const float* __restrict__ protos,
    float* __restrict__ out)
{
    int idx = blockIdx.x * 256 + threadIdx.x;
    if (idx >= 32 * NQB * NWAY) return;
    int b = idx / (NQB * NWAY);
    int r = idx - b * (NQB * NWAY);
    int q = r / NWAY;
    int w = r - q * NWAY;
    const float* qf = feat_q + (size_t)(b * NQB + q) * 128;
    const float* pp = protos + (size_t)(b * NWAY + w) * 128;
    float d2 = 0.f;
    #pragma unroll 4
    for (int i = 0; i < 128; ++i) { float d = qf[i] - pp[i]; d2 += d * d; }
    out[idx] = -sqrtf(fmaxf(d2, 0.f));
}

// ---------------------------------------------------------------------------
extern "C" void kernel_launch(void* const* d_in, const int* in_sizes, int n_in,
                              void* d_out, int out_size, void* d_ws, size_t ws_size,
                              hipStream_t stream) {
    const float* s_img = (const float*)d_in[0];
    const float* q_img = (const float*)d_in[1];
    const int*   s_lab = (const int*)d_in[2];
    const float* pw1  = (const float*)d_in[3];
    const float* pb1  = (const float*)d_in[4];
    const float* pg1  = (const float*)d_in[5];
    const float* pbe1 = (const float*)d_in[6];
    const float* pm1  = (const float*)d_in[7];
    const float* pv1  = (const float*)d_in[8];
    const float* pw2  = (const float*)d_in[9];
    const float* pb2  = (const float*)d_in[10];
    const float* pg2  = (const float*)d_in[11];
    const float* pbe2 = (const float*)d_in[12];
    const float* pm2  = (const float*)d_in[13];
    const float* pv2  = (const float*)d_in[14];
    const float* pw3  = (const float*)d_in[15];
    const float* pb3  = (const float*)d_in[16];
    const float* pg3  = (const float*)d_in[17];
    const float* pbe3 = (const float*)d_in[18];
    const float* pm3  = (const float*)d_in[19];
    const float* pv3  = (const float*)d_in[20];
    const float* pwf  = (const float*)d_in[21];
    const float* pbf  = (const float*)d_in[22];
    const float* pgf  = (const float*)d_in[23];
    const float* pbef = (const float*)d_in[24];
    const float* pmf  = (const float*)d_in[25];
    const float* pvf  = (const float*)d_in[26];

    const size_t feat_elems = (size_t)NSAMP * 128;      // fp32
    const size_t prot_elems = (size_t)32 * NWAY * 128;  // fp32
    const size_t wf2_shorts = 12288;                    // 24 frags x 512
    // wf3: 96 frags x 512 shorts

    float* feat   = (float*)d_ws;
    float* protos = feat + feat_elems;
    unsigned short* Wf2 = (unsigned short*)(protos + prot_elems);
    unsigned short* Wf3 = Wf2 + wf2_shorts;
    float* out = (float*)d_out;

    prep_weights<<<120, 256, 0, stream>>>(pw2, pw3, Wf2, Wf3);

    encoder_fused<<<NSAMP, 256, 0, stream>>>(
        s_img, q_img,
        pw1, pb1, pg1, pbe1, pm1, pv1,
        pb2, pg2, pbe2, pm2, pv2, Wf2,
        pb3, pg3, pbe3, pm3, pv3, Wf3,
        pwf, pbf, pgf, pbef, pmf, pvf,
        feat);

    proto_kernel<<<32 * NWAY, 128, 0, stream>>>(feat, s_lab, protos);

    dist_kernel<<<(32 * NQB * NWAY + 255) / 256, 256, 0, stream>>>(
        feat + (size_t)NSUP * 128, protos, out);
}

// Round 7
// 681.686 us; speedup vs baseline: 1.1160x; 1.1160x over previous
//
#include <hip/hip_runtime.h>
#include <math.h>

#define EPS_BN 1e-5f

// Problem constants: B=32, NS=200, NQ=100, C=8, L=512, H=32, F=128, N_WAY=20
#define NSUP   6400
#define NQRY   3200
#define NSAMP  9600
#define NWAY   20
#define NSHOTB 200
#define NQB    100

using short8  = __attribute__((ext_vector_type(8))) short;
using floatx4 = __attribute__((ext_vector_type(4))) float;

// accurate split (prep only): RNE both halves
__device__ __forceinline__ void bf16_split_rn(float x, unsigned& uh, unsigned& ul) {
    unsigned u = __float_as_uint(x);
    uh = (u + 0x7FFFu + ((u >> 16) & 1u)) >> 16;
    float e = x - __uint_as_float(uh << 16);
    unsigned ue = __float_as_uint(e);
    ul = (ue + 0x7FFFu + ((ue >> 16) & 1u)) >> 16;
}
// fast split (hot path): RNE hi, truncated lo (lo err ~2^-17 |x|)
__device__ __forceinline__ void bf16_split_fast(float x, unsigned& uh, unsigned& ul) {
    unsigned u = __float_as_uint(x);
    uh = (u + 0x7FFFu + ((u >> 16) & 1u)) >> 16;
    float e = x - __uint_as_float(uh << 16);
    ul = __float_as_uint(e) >> 16;
}

// ===========================================================================
// prep: W2 [64][32][3], W3 [128][64][3], W1 [32][8][3] -> MFMA B-fragment
// order, split hi/lo bf16. W2/W3 layouts identical to rounds 4-6 (verified).
//  W2: frag=(t*4+nt)*2+hl;        co=nt*16+(lane&15), ci=(lane>>4)*8+j
//  W3: frag=((t*2+ks)*8+nt)*2+hl; co=nt*16+(lane&15), ci=ks*32+(lane>>4)*8+j
//  W1: frag=nt*2+hl;              co=nt*16+(lane&15), k=quad*8+j -> t=quad,
//      ci=j; zero for t==3 (K padded 24->32)
// ===========================================================================
__global__ __launch_bounds__(256) void prep_weights(
    const float* __restrict__ w1, const float* __restrict__ w2,
    const float* __restrict__ w3, unsigned short* __restrict__ Wf1,
    unsigned short* __restrict__ Wf2, unsigned short* __restrict__ Wf3)
{
    int b = blockIdx.x;
    if (b < 24) {                         // W2: 24 frags x 512
        int e = b * 512 + threadIdx.x;
        #pragma unroll
        for (int r = 0; r < 2; ++r, e += 256) {
            int frag = e >> 9, off = e & 511;
            int lane = off >> 3, j = off & 7;
            int hl = frag & 1, f2 = frag >> 1;
            int nt = f2 & 3, t = f2 >> 2;
            int co = nt * 16 + (lane & 15);
            int ci = (lane >> 4) * 8 + j;
            float x = w2[(co * 32 + ci) * 3 + t];
            unsigned uh, ul; bf16_split_rn(x, uh, ul);
            Wf2[e] = (unsigned short)(hl ? ul : uh);
        }
    } else if (b < 120) {                 // W3: 96 frags x 512
        int e = (b - 24) * 512 + threadIdx.x;
        #pragma unroll
        for (int r = 0; r < 2; ++r, e += 256) {
            int frag = e >> 9, off = e & 511;
            int lane = off >> 3, j = off & 7;
            int hl = frag & 1, f2 = frag >> 1;
            int nt = f2 & 7, f3 = f2 >> 3;
            int ks = f3 & 1, t = f3 >> 1;
            int co = nt * 16 + (lane & 15);
            int ci = ks * 32 + (lane >> 4) * 8 + j;
            float x = w3[(co * 64 + ci) * 3 + t];
            unsigned uh, ul; bf16_split_rn(x, uh, ul);
            Wf3[e] = (unsigned short)(hl ? ul : uh);
        }
    } else {                              // W1: 4 frags x 512
        int e = (b - 120) * 512 + threadIdx.x;
        #pragma unroll
        for (int r = 0; r < 2; ++r, e += 256) {
            int frag = e >> 9, off = e & 511;
            int lane = off >> 3, j = off & 7;
            int hl = frag & 1, nt = frag >> 1;
            int co = nt * 16 + (lane & 15);
            int t  = lane >> 4;           // quad = tap (K = t*8+ci)
            float x = (t < 3) ? w1[(co * 8 + j) * 3 + t] : 0.f;
            unsigned uh, ul; bf16_split_rn(x, uh, ul);
            Wf1[e] = (unsigned short)(hl ? ul : uh);
        }
    }
}

// ===========================================================================
// Fused encoder, all-MFMA convs:
//  conv1: im2col (K=24 pad 32) built per 64-row chunk directly from global,
//         4-term split-bf16 MFMA -> BN/ReLU/pool -> B1 (split bf16, LDS)
//  conv2: r6-verified MFMA (3-term), epilogue -> X2 (split bf16, LDS)
//  conv3: r6-verified MFMA (3-term), epilogue -> mean -> linear -> norm
// ===========================================================================
__global__ __launch_bounds__(256, 3) void encoder_fused(
    const float* __restrict__ s_img, const float* __restrict__ q_img,
    const unsigned short* __restrict__ Wf1,
    const float* __restrict__ pb1, const float* __restrict__ pg1,
    const float* __restrict__ pbe1, const float* __restrict__ pm1,
    const float* __restrict__ pv1,
    const float* __restrict__ pb2, const float* __restrict__ pg2,
    const float* __restrict__ pbe2, const float* __restrict__ pm2,
    const float* __restrict__ pv2, const unsigned short* __restrict__ Wf2,
    const float* __restrict__ pb3, const float* __restrict__ pg3,
    const float* __restrict__ pbe3, const float* __restrict__ pm3,
    const float* __restrict__ pv3, const unsigned short* __restrict__ Wf3,
    const float* __restrict__ pwf, const float* __restrict__ pbf,
    const float* __restrict__ pgf, const float* __restrict__ pbef,
    const float* __restrict__ pmf, const float* __restrict__ pvf,
    float* __restrict__ feat_out)
{
    // U regions (time-multiplexed):
    //  conv1/conv2 phase: B1h @0 (20640 B), B1l @20640 (20640 B),
    //                     Aimh @41280 (4096 B), Aiml @45376 (4096 B)
    //  conv3 phase:       X2h @0 (18720 B), X2l @18720 (18720 B)
    __shared__ __align__(16) char U[49472];
    short* const B1h  = (short*)U;
    short* const B1l  = (short*)(U + 20640);
    short* const Aimh = (short*)(U + 41280);   // 64 rows x 32 shorts
    short* const Aiml = (short*)(U + 45376);
    short* const X2h  = (short*)U;
    short* const X2l  = (short*)(U + 18720);
    __shared__ float sc1[32], sh1[32], sc2[64], sh2[64], sc3[128], sh3[128];
    __shared__ float part[2][128];
    __shared__ float featm[128], featr[128];

    const int tid  = threadIdx.x;
    const int sid  = blockIdx.x;
    const int lane = tid & 63;
    const int wid  = tid >> 6;
    const int mrow = lane & 15;
    const int quad = lane >> 4;
    const int kq   = quad * 8;

    const float* xin = (sid < NSUP) ? (s_img + (size_t)sid * 4096)
                                    : (q_img + (size_t)(sid - NSUP) * 4096);

    // ---- fold BN params ----
    if (tid < 32) {
        float s = pg1[tid] * rsqrtf(pv1[tid] + EPS_BN);
        sc1[tid] = s; sh1[tid] = (pb1[tid] - pm1[tid]) * s + pbe1[tid];
    } else if (tid < 96) {
        int c = tid - 32;
        float s = pg2[c] * rsqrtf(pv2[c] + EPS_BN);
        sc2[c] = s; sh2[c] = (pb2[c] - pm2[c]) * s + pbe2[c];
    } else if (tid < 224) {
        int c = tid - 96;
        float s = pg3[c] * rsqrtf(pv3[c] + EPS_BN);
        sc3[c] = s; sh3[c] = (pb3[c] - pm3[c]) * s + pbe3[c];
    }
    // zero im2col pad cols 24..31 (stays zero across chunks)
    {
        int row = tid >> 2, cw = tid & 3;
        ((unsigned*)(Aimh + row*32 + 24))[cw] = 0;
        ((unsigned*)(Aiml + row*32 + 24))[cw] = 0;
    }
    // preload conv1 W fragments (persist in VGPRs)
    short8 W1h[2], W1l[2];
    #pragma unroll
    for (int nt = 0; nt < 2; ++nt) {
        W1h[nt] = *(const short8*)(Wf1 + ((nt*2 + 0)*512 + lane*8));
        W1l[nt] = *(const short8*)(Wf1 + ((nt*2 + 1)*512 + lane*8));
    }
    __syncthreads();

    // ---- conv1: 8 chunks of 64 pre-pool rows ----
    for (int c = 0; c < 8; ++c) {
        // build im2col: Aim[r][t*8+ci] = X[ci][c*64 + r - 1 + t]
        for (int v = tid; v < 528; v += 256) {
            int ci = v / 66;
            int jo = v - ci * 66;              // 0..65
            int j  = c*64 - 1 + jo;
            float x = (j >= 0 && j < 512) ? xin[ci*512 + j] : 0.f;
            unsigned uh, ul; bf16_split_fast(x, uh, ul);
            #pragma unroll
            for (int t = 0; t < 3; ++t) {
                int r = jo - t;
                if (r >= 0 && r < 64) {
                    Aimh[r*32 + t*8 + ci] = (short)uh;
                    Aiml[r*32 + t*8 + ci] = (short)ul;
                }
            }
        }
        __syncthreads();
        // MFMA: wave owns rows [wid*16, wid*16+16), 4-term split
        floatx4 a1[2] = {};
        {
            const int base = (wid*16 + mrow)*32 + kq;
            const short8 Ah = *(const short8*)&Aimh[base];
            const short8 Al = *(const short8*)&Aiml[base];
            #pragma unroll
            for (int nt = 0; nt < 2; ++nt) {
                a1[nt] = __builtin_amdgcn_mfma_f32_16x16x32_bf16(Ah, W1h[nt], a1[nt], 0, 0, 0);
                a1[nt] = __builtin_amdgcn_mfma_f32_16x16x32_bf16(Ah, W1l[nt], a1[nt], 0, 0, 0);
                a1[nt] = __builtin_amdgcn_mfma_f32_16x16x32_bf16(Al, W1h[nt], a1[nt], 0, 0, 0);
                a1[nt] = __builtin_amdgcn_mfma_f32_16x16x32_bf16(Al, W1l[nt], a1[nt], 0, 0, 0);
            }
        }
        // epilogue: BN+ReLU+pool2 -> B1 rows (pl = c*32 + wid*8 + quad*2 + {0,1})
        {
            const int pl0 = c*32 + wid*8 + quad*2 + 1;   // +1 halo
            #pragma unroll
            for (int nt = 0; nt < 2; ++nt) {
                const int co = nt*16 + mrow;
                const float sc = sc1[co], sh = sh1[co];
                floatx4 d = a1[nt];
                float v0 = fmaxf(0.f, fmaxf(d[0]*sc + sh, d[1]*sc + sh));
                float v1 = fmaxf(0.f, fmaxf(d[2]*sc + sh, d[3]*sc + sh));
                unsigned uh, ul;
                bf16_split_fast(v0, uh, ul);
                B1h[pl0*40 + co] = (short)uh; B1l[pl0*40 + co] = (short)ul;
                bf16_split_fast(v1, uh, ul);
                B1h[(pl0+1)*40 + co] = (short)uh; B1l[(pl0+1)*40 + co] = (short)ul;
            }
        }
        __syncthreads();   // protect Aim for next chunk
    }
    // B1 halo rows 0, 257
    if (tid < 40) {
        B1h[tid] = 0; B1l[tid] = 0;
        B1h[257*40 + tid] = 0; B1l[257*40 + tid] = 0;
    }
    __syncthreads();

    // ---- conv2 MFMA (r6-verified): M=256, N=64, K=32, 3 taps, 3-term.
    // Wave w owns mt {4w..4w+3} x ALL nt {0..3}.
    floatx4 acc2[4][4] = {};
    for (int t = 0; t < 3; ++t) {
        short8 W2h[4], W2l[4];
        #pragma unroll
        for (int nt = 0; nt < 4; ++nt) {
            W2h[nt] = *(const short8*)(Wf2 + (((t*4 + nt)*2 + 0)*512 + lane*8));
            W2l[nt] = *(const short8*)(Wf2 + (((t*4 + nt)*2 + 1)*512 + lane*8));
        }
        #pragma unroll
        for (int mi = 0; mi < 4; ++mi) {
            const int mt = wid*4 + mi;
            const int base = (mt*16 + mrow + t)*40 + kq;
            const short8 Ah = *(const short8*)&B1h[base];
            const short8 Al = *(const short8*)&B1l[base];
            #pragma unroll
            for (int nt = 0; nt < 4; ++nt) {
                acc2[mi][nt] = __builtin_amdgcn_mfma_f32_16x16x32_bf16(Ah, W2h[nt], acc2[mi][nt], 0, 0, 0);
                acc2[mi][nt] = __builtin_amdgcn_mfma_f32_16x16x32_bf16(Ah, W2l[nt], acc2[mi][nt], 0, 0, 0);
                acc2[mi][nt] = __builtin_amdgcn_mfma_f32_16x16x32_bf16(Al, W2h[nt], acc2[mi][nt], 0, 0, 0);
            }
        }
    }
    __syncthreads();   // B1 dead

    // ---- conv2 epilogue -> X2 (BN+ReLU+pool2, split bf16) ----
    {
        #pragma unroll
        for (int mi = 0; mi < 4; ++mi) {
            const int mt = wid*4 + mi;
            const int r0 = mt*8 + quad*2 + 1;
            #pragma unroll
            for (int nt = 0; nt < 4; ++nt) {
                const int co = nt*16 + mrow;
                const float sc = sc2[co], sh = sh2[co];
                floatx4 d = acc2[mi][nt];
                float v0 = fmaxf(0.f, fmaxf(d[0]*sc + sh, d[1]*sc + sh));
                float v1 = fmaxf(0.f, fmaxf(d[2]*sc + sh, d[3]*sc + sh));
                unsigned uh, ul;
                bf16_split_fast(v0, uh, ul);
                X2h[r0*72 + co] = (short)uh; X2l[r0*72 + co] = (short)ul;
                bf16_split_fast(v1, uh, ul);
                X2h[(r0+1)*72 + co] = (short)uh; X2l[(r0+1)*72 + co] = (short)ul;
            }
        }
        if (tid < 72) {
            X2h[tid] = 0; X2l[tid] = 0;
            X2h[129*72 + tid] = 0; X2l[129*72 + tid] = 0;
        }
    }
    __syncthreads();

    // ---- conv3 MFMA (r6-verified): M=128, N=128, K=64, 3 taps, 3-term.
    // Wave w: mt {(w&1)*4..+3} x nt {(w>>1)*4..+3}.
    floatx4 acc3[4][4] = {};
    const int mt0 = (wid & 1) * 4;
    const int ntb = (wid >> 1) * 4;
    for (int t = 0; t < 3; ++t) {
        for (int ks = 0; ks < 2; ++ks) {
            const int fb = (t*2 + ks) * 8;
            short8 W3h[4], W3l[4];
            #pragma unroll
            for (int n = 0; n < 4; ++n) {
                W3h[n] = *(const short8*)(Wf3 + (((fb + ntb + n)*2 + 0)*512 + lane*8));
                W3l[n] = *(const short8*)(Wf3 + (((fb + ntb + n)*2 + 1)*512 + lane*8));
            }
            #pragma unroll
            for (int mi = 0; mi < 4; ++mi) {
                const int base = ((mt0 + mi)*16 + mrow + t)*72 + ks*32 + kq;
                const short8 Ah = *(const short8*)&X2h[base];
                const short8 Al = *(const short8*)&X2l[base];
                #pragma unroll
                for (int n = 0; n < 4; ++n) {
                    acc3[mi][n] = __builtin_amdgcn_mfma_f32_16x16x32_bf16(Ah, W3h[n], acc3[mi][n], 0, 0, 0);
                    acc3[mi][n] = __builtin_amdgcn_mfma_f32_16x16x32_bf16(Ah, W3l[n], acc3[mi][n], 0, 0, 0);
                    acc3[mi][n] = __builtin_amdgcn_mfma_f32_16x16x32_bf16(Al, W3h[n], acc3[mi][n], 0, 0, 0);
                }
            }
        }
    }

    // ---- conv3 epilogue: BN+ReLU+pool2+mean, 2-wave partial reduction ----
    {
        float s[4] = {0.f, 0.f, 0.f, 0.f};
        #pragma unroll
        for (int n = 0; n < 4; ++n) {
            const int co = (ntb + n)*16 + mrow;
            const float sc = sc3[co], sh = sh3[co];
            #pragma unroll
            for (int mi = 0; mi < 4; ++mi) {
                floatx4 d = acc3[mi][n];
                s[n] += fmaxf(0.f, fmaxf(d[0]*sc + sh, d[1]*sc + sh));
                s[n] += fmaxf(0.f, fmaxf(d[2]*sc + sh, d[3]*sc + sh));
            }
        }
        #pragma unroll
        for (int n = 0; n < 4; ++n) {
            s[n] += __shfl_xor(s[n], 16);
            s[n] += __shfl_xor(s[n], 32);
        }
        if (lane < 16) {
            #pragma unroll
            for (int n = 0; n < 4; ++n)
                part[wid & 1][(ntb + n)*16 + lane] = s[n];
        }
    }
    __syncthreads();
    if (tid < 128) featm[tid] = (part[0][tid] + part[1][tid]) * (1.0f / 64.0f);
    __syncthreads();

    // ---- linear 128->128 + BN + ReLU ----
    if (tid < 128) {
        const float* wr = pwf + (size_t)tid * 128;
        float s = 0.f;
        #pragma unroll 4
        for (int i = 0; i < 128; i += 4) {
            float4 w4 = *(const float4*)(wr + i);
            s += w4.x*featm[i] + w4.y*featm[i+1] + w4.z*featm[i+2] + w4.w*featm[i+3];
        }
        s += pbf[tid];
        s = (s - pmf[tid]) * (pgf[tid] * rsqrtf(pvf[tid] + EPS_BN)) + pbef[tid];
        featr[tid] = fmaxf(s, 0.f);
    }
    __syncthreads();

    // ---- L2 normalize ----
    if (tid < 128) {
        float ss = 0.f;
        for (int i = 0; i < 128; ++i) ss += featr[i] * featr[i];
        float n = fmaxf(sqrtf(ss), 1e-12f);
        feat_out[(size_t)sid * 128 + tid] = featr[tid] / n;
    }
}

// ===========================================================================
// Fused prototypes + distances: one block per batch element b.
// Protos built in LDS, then all NQB x NWAY distances for b.
// ===========================================================================
__global__ __launch_bounds__(256) void proto_dist_kernel(
    const float* __restrict__ feat_s, const float* __restrict__ feat_q,
    const int* __restrict__ s_lab, float* __restrict__ out)
{
    __shared__ float P[NWAY * 128];
    __shared__ float cntv[NWAY];
    const int b = blockIdx.x;
    const int tid = threadIdx.x;

    for (int i = tid; i < NWAY*128; i += 256) P[i] = 0.f;
    __syncthreads();

    const float* sf = feat_s + (size_t)b * NSHOTB * 128;
    const int* lab = s_lab + b * NSHOTB;
    if (tid < 128) {
        for (int s = 0; s < NSHOTB; ++s) {
            int w = lab[s];                      // wave-uniform -> scalar
            P[w*128 + tid] += sf[s*128 + tid];
        }
    } else if (tid < 128 + NWAY) {
        int w = tid - 128, c = 0;
        for (int s = 0; s < NSHOTB; ++s) c += (lab[s] == w);
        cntv[w] = (float)c;
    }
    __syncthreads();
    for (int i = tid; i < NWAY*128; i += 256) P[i] /= cntv[i >> 7];
    __syncthreads();

    const float* qb = feat_q + (size_t)b * NQB * 128;
    float* ob = out + (size_t)b * NQB * NWAY;
    for (int o = tid; o < NQB*NWAY; o += 256) {
        int q = o / NWAY, w = o - q*NWAY;
        const float* qf = qb + q*128;
        const float* pp = &P[w*128];
        float d2 = 0.f;
        #pragma unroll 8
        for (int i = 0; i < 128; i += 4) {
            float4 qv = *(const float4*)(qf + i);
            float d0 = qv.x - pp[i+0], d1 = qv.y - pp[i+1];
            float d2v = qv.z - pp[i+2], d3 = qv.w - pp[i+3];
            d2 += d0*d0 + d1*d1 + d2v*d2v + d3*d3;
        }
        ob[o] = -sqrtf(fmaxf(d2, 0.f));
    }
}

// ---------------------------------------------------------------------------
extern "C" void kernel_launch(void* const* d_in, const int* in_sizes, int n_in,
                              void* d_out, int out_size, void* d_ws, size_t ws_size,
                              hipStream_t stream) {
    const float* s_img = (const float*)d_in[0];
    const float* q_img = (const float*)d_in[1];
    const int*   s_lab = (const int*)d_in[2];
    const float* pw1  = (const float*)d_in[3];
    const float* pb1  = (const float*)d_in[4];
    const float* pg1  = (const float*)d_in[5];
    const float* pbe1 = (const float*)d_in[6];
    const float* pm1  = (const float*)d_in[7];
    const float* pv1  = (const float*)d_in[8];
    const float* pw2  = (const float*)d_in[9];
    const float* pb2  = (const float*)d_in[10];
    const float* pg2  = (const float*)d_in[11];
    const float* pbe2 = (const float*)d_in[12];
    const float* pm2  = (const float*)d_in[13];
    const float* pv2  = (const float*)d_in[14];
    const float* pw3  = (const float*)d_in[15];
    const float* pb3  = (const float*)d_in[16];
    const float* pg3  = (const float*)d_in[17];
    const float* pbe3 = (const float*)d_in[18];
    const float* pm3  = (const float*)d_in[19];
    const float* pv3  = (const float*)d_in[20];
    const float* pwf  = (const float*)d_in[21];
    const float* pbf  = (const float*)d_in[22];
    const float* pgf  = (const float*)d_in[23];
    const float* pbef = (const float*)d_in[24];
    const float* pmf  = (const float*)d_in[25];
    const float* pvf  = (const float*)d_in[26];

    const size_t feat_elems = (size_t)NSAMP * 128;   // fp32
    float* feat = (float*)d_ws;
    unsigned short* Wf1 = (unsigned short*)(feat + feat_elems);
    unsigned short* Wf2 = Wf1 + 2048;    // 4  frags x 512
    unsigned short* Wf3 = Wf2 + 12288;   // 24 frags x 512; W3 = 96 x 512
    float* out = (float*)d_out;

    prep_weights<<<124, 256, 0, stream>>>(pw1, pw2, pw3, Wf1, Wf2, Wf3);

    encoder_fused<<<NSAMP, 256, 0, stream>>>(
        s_img, q_img,
        Wf1, pb1, pg1, pbe1, pm1, pv1,
        pb2, pg2, pbe2, pm2, pv2, Wf2,
        pb3, pg3, pbe3, pm3, pv3, Wf3,
        pwf, pbf, pgf, pbef, pmf, pvf,
        feat);

    proto_dist_kernel<<<32, 256, 0, stream>>>(
        feat, feat + (size_t)NSUP * 128, s_lab, out);
}

// Round 8
// 625.277 us; speedup vs baseline: 1.2167x; 1.0902x over previous
//
#include <hip/hip_runtime.h>
#include <math.h>

#define EPS_BN 1e-5f

// Problem constants: B=32, NS=200, NQ=100, C=8, L=512, H=32, F=128, N_WAY=20
#define NSUP   6400
#define NQRY   3200
#define NSAMP  9600
#define NWAY   20
#define NSHOTB 200
#define NQB    100

using short8  = __attribute__((ext_vector_type(8))) short;
using floatx4 = __attribute__((ext_vector_type(4))) float;

// accurate split (prep only): RNE both halves
__device__ __forceinline__ void bf16_split_rn(float x, unsigned& uh, unsigned& ul) {
    unsigned u = __float_as_uint(x);
    uh = (u + 0x7FFFu + ((u >> 16) & 1u)) >> 16;
    float e = x - __uint_as_float(uh << 16);
    unsigned ue = __float_as_uint(e);
    ul = (ue + 0x7FFFu + ((ue >> 16) & 1u)) >> 16;
}
// fast split (hot path): RNE hi, truncated lo
__device__ __forceinline__ void bf16_split_fast(float x, unsigned& uh, unsigned& ul) {
    unsigned u = __float_as_uint(x);
    uh = (u + 0x7FFFu + ((u >> 16) & 1u)) >> 16;
    float e = x - __uint_as_float(uh << 16);
    ul = __float_as_uint(e) >> 16;
}

// ===========================================================================
// prep: W1 [32][8][3], W2 [64][32][3], W3 [128][64][3] -> MFMA B-fragment
// order, split hi/lo bf16 (layouts verified rounds 4-7).
// ===========================================================================
__global__ __launch_bounds__(256) void prep_weights(
    const float* __restrict__ w1, const float* __restrict__ w2,
    const float* __restrict__ w3, unsigned short* __restrict__ Wf1,
    unsigned short* __restrict__ Wf2, unsigned short* __restrict__ Wf3)
{
    int b = blockIdx.x;
    if (b < 24) {                         // W2: 24 frags x 512
        int e = b * 512 + threadIdx.x;
        #pragma unroll
        for (int r = 0; r < 2; ++r, e += 256) {
            int frag = e >> 9, off = e & 511;
            int lane = off >> 3, j = off & 7;
            int hl = frag & 1, f2 = frag >> 1;
            int nt = f2 & 3, t = f2 >> 2;
            int co = nt * 16 + (lane & 15);
            int ci = (lane >> 4) * 8 + j;
            float x = w2[(co * 32 + ci) * 3 + t];
            unsigned uh, ul; bf16_split_rn(x, uh, ul);
            Wf2[e] = (unsigned short)(hl ? ul : uh);
        }
    } else if (b < 120) {                 // W3: 96 frags x 512
        int e = (b - 24) * 512 + threadIdx.x;
        #pragma unroll
        for (int r = 0; r < 2; ++r, e += 256) {
            int frag = e >> 9, off = e & 511;
            int lane = off >> 3, j = off & 7;
            int hl = frag & 1, f2 = frag >> 1;
            int nt = f2 & 7, f3 = f2 >> 3;
            int ks = f3 & 1, t = f3 >> 1;
            int co = nt * 16 + (lane & 15);
            int ci = ks * 32 + (lane >> 4) * 8 + j;
            float x = w3[(co * 64 + ci) * 3 + t];
            unsigned uh, ul; bf16_split_rn(x, uh, ul);
            Wf3[e] = (unsigned short)(hl ? ul : uh);
        }
    } else {                              // W1: 4 frags x 512
        int e = (b - 120) * 512 + threadIdx.x;
        #pragma unroll
        for (int r = 0; r < 2; ++r, e += 256) {
            int frag = e >> 9, off = e & 511;
            int lane = off >> 3, j = off & 7;
            int hl = frag & 1, nt = frag >> 1;
            int co = nt * 16 + (lane & 15);
            int t  = lane >> 4;           // quad = tap (K = t*8+ci)
            float x = (t < 3) ? w1[(co * 8 + j) * 3 + t] : 0.f;
            unsigned uh, ul; bf16_split_rn(x, uh, ul);
            Wf1[e] = (unsigned short)(hl ? ul : uh);
        }
    }
}

// ===========================================================================
// Fused encoder, all-MFMA convs. Round-7 structure with Aim row stride
// padded 32 -> 40 shorts (80 B, 20-bank hop, gcd(20,32)=4): conv1 im2col
// writes spread over 8 bank-starts, A-frag b128 reads land 2 lanes/bank
// (free). part/featm/featr alias the Aim region (dead after conv1) to keep
// LDS <= ~53 KB -> 3 blocks/CU.
// ===========================================================================
__global__ __launch_bounds__(256, 3) void encoder_fused(
    const float* __restrict__ s_img, const float* __restrict__ q_img,
    const unsigned short* __restrict__ Wf1,
    const float* __restrict__ pb1, const float* __restrict__ pg1,
    const float* __restrict__ pbe1, const float* __restrict__ pm1,
    const float* __restrict__ pv1,
    const float* __restrict__ pb2, const float* __restrict__ pg2,
    const float* __restrict__ pbe2, const float* __restrict__ pm2,
    const float* __restrict__ pv2, const unsigned short* __restrict__ Wf2,
    const float* __restrict__ pb3, const float* __restrict__ pg3,
    const float* __restrict__ pbe3, const float* __restrict__ pm3,
    const float* __restrict__ pv3, const unsigned short* __restrict__ Wf3,
    const float* __restrict__ pwf, const float* __restrict__ pbf,
    const float* __restrict__ pgf, const float* __restrict__ pbef,
    const float* __restrict__ pmf, const float* __restrict__ pvf,
    float* __restrict__ feat_out)
{
    // U regions (time-multiplexed):
    //  conv1/conv2: B1h @0 (20640), B1l @20640 (20640),
    //               Aimh @41280 (64x40x2 = 5120), Aiml @46400 (5120)
    //  conv3:       X2h @0 (18720), X2l @18720 (18720)
    //  tail:        part @41280 (1024), featm @42304 (512), featr @42816 (512)
    __shared__ __align__(16) char U[51520];
    short* const B1h  = (short*)U;
    short* const B1l  = (short*)(U + 20640);
    short* const Aimh = (short*)(U + 41280);
    short* const Aiml = (short*)(U + 46400);
    short* const X2h  = (short*)U;
    short* const X2l  = (short*)(U + 18720);
    float* const part  = (float*)(U + 41280);   // [2][128]
    float* const featm = (float*)(U + 42304);   // [128]
    float* const featr = (float*)(U + 42816);   // [128]
    __shared__ float sc1[32], sh1[32], sc2[64], sh2[64], sc3[128], sh3[128];

    const int tid  = threadIdx.x;
    const int sid  = blockIdx.x;
    const int lane = tid & 63;
    const int wid  = tid >> 6;
    const int mrow = lane & 15;
    const int quad = lane >> 4;
    const int kq   = quad * 8;

    const float* xin = (sid < NSUP) ? (s_img + (size_t)sid * 4096)
                                    : (q_img + (size_t)(sid - NSUP) * 4096);

    // ---- fold BN params ----
    if (tid < 32) {
        float s = pg1[tid] * rsqrtf(pv1[tid] + EPS_BN);
        sc1[tid] = s; sh1[tid] = (pb1[tid] - pm1[tid]) * s + pbe1[tid];
    } else if (tid < 96) {
        int c = tid - 32;
        float s = pg2[c] * rsqrtf(pv2[c] + EPS_BN);
        sc2[c] = s; sh2[c] = (pb2[c] - pm2[c]) * s + pbe2[c];
    } else if (tid < 224) {
        int c = tid - 96;
        float s = pg3[c] * rsqrtf(pv3[c] + EPS_BN);
        sc3[c] = s; sh3[c] = (pb3[c] - pm3[c]) * s + pbe3[c];
    }
    // zero im2col K-pad cols 24..31 (stays zero across chunks)
    {
        int row = tid >> 2, cw = tid & 3;
        ((unsigned*)(Aimh + row*40 + 24))[cw] = 0;
        ((unsigned*)(Aiml + row*40 + 24))[cw] = 0;
    }
    // preload conv1 W fragments (persist in VGPRs)
    short8 W1h[2], W1l[2];
    #pragma unroll
    for (int nt = 0; nt < 2; ++nt) {
        W1h[nt] = *(const short8*)(Wf1 + ((nt*2 + 0)*512 + lane*8));
        W1l[nt] = *(const short8*)(Wf1 + ((nt*2 + 1)*512 + lane*8));
    }
    __syncthreads();

    // ---- conv1: 8 chunks of 64 pre-pool rows, im2col + MFMA ----
    for (int c = 0; c < 8; ++c) {
        // build im2col: Aim[r][t*8+ci] = X[ci][c*64 + r - 1 + t]
        for (int v = tid; v < 528; v += 256) {
            int ci = v / 66;
            int jo = v - ci * 66;              // 0..65
            int j  = c*64 - 1 + jo;
            float x = (j >= 0 && j < 512) ? xin[ci*512 + j] : 0.f;
            unsigned uh, ul; bf16_split_fast(x, uh, ul);
            #pragma unroll
            for (int t = 0; t < 3; ++t) {
                int r = jo - t;
                if (r >= 0 && r < 64) {
                    Aimh[r*40 + t*8 + ci] = (short)uh;
                    Aiml[r*40 + t*8 + ci] = (short)ul;
                }
            }
        }
        __syncthreads();
        // MFMA: wave owns rows [wid*16, wid*16+16), 4-term split
        floatx4 a1[2] = {};
        {
            const int base = (wid*16 + mrow)*40 + kq;
            const short8 Ah = *(const short8*)&Aimh[base];
            const short8 Al = *(const short8*)&Aiml[base];
            #pragma unroll
            for (int nt = 0; nt < 2; ++nt) {
                a1[nt] = __builtin_amdgcn_mfma_f32_16x16x32_bf16(Ah, W1h[nt], a1[nt], 0, 0, 0);
                a1[nt] = __builtin_amdgcn_mfma_f32_16x16x32_bf16(Ah, W1l[nt], a1[nt], 0, 0, 0);
                a1[nt] = __builtin_amdgcn_mfma_f32_16x16x32_bf16(Al, W1h[nt], a1[nt], 0, 0, 0);
                a1[nt] = __builtin_amdgcn_mfma_f32_16x16x32_bf16(Al, W1l[nt], a1[nt], 0, 0, 0);
            }
        }
        // epilogue: BN+ReLU+pool2 -> B1 rows
        {
            const int pl0 = c*32 + wid*8 + quad*2 + 1;   // +1 halo
            #pragma unroll
            for (int nt = 0; nt < 2; ++nt) {
                const int co = nt*16 + mrow;
                const float sc = sc1[co], sh = sh1[co];
                floatx4 d = a1[nt];
                float v0 = fmaxf(0.f, fmaxf(d[0]*sc + sh, d[1]*sc + sh));
                float v1 = fmaxf(0.f, fmaxf(d[2]*sc + sh, d[3]*sc + sh));
                unsigned uh, ul;
                bf16_split_fast(v0, uh, ul);
                B1h[pl0*40 + co] = (short)uh; B1l[pl0*40 + co] = (short)ul;
                bf16_split_fast(v1, uh, ul);
                B1h[(pl0+1)*40 + co] = (short)uh; B1l[(pl0+1)*40 + co] = (short)ul;
            }
        }
        __syncthreads();   // protect Aim for next chunk
    }
    // B1 halo rows 0, 257
    if (tid < 40) {
        B1h[tid] = 0; B1l[tid] = 0;
        B1h[257*40 + tid] = 0; B1l[257*40 + tid] = 0;
    }
    __syncthreads();

    // ---- conv2 MFMA: M=256, N=64, K=32, 3 taps, 3-term.
    // Wave w owns mt {4w..4w+3} x ALL nt {0..3}.
    floatx4 acc2[4][4] = {};
    for (int t = 0; t < 3; ++t) {
        short8 W2h[4], W2l[4];
        #pragma unroll
        for (int nt = 0; nt < 4; ++nt) {
            W2h[nt] = *(const short8*)(Wf2 + (((t*4 + nt)*2 + 0)*512 + lane*8));
            W2l[nt] = *(const short8*)(Wf2 + (((t*4 + nt)*2 + 1)*512 + lane*8));
        }
        #pragma unroll
        for (int mi = 0; mi < 4; ++mi) {
            const int mt = wid*4 + mi;
            const int base = (mt*16 + mrow + t)*40 + kq;
            const short8 Ah = *(const short8*)&B1h[base];
            const short8 Al = *(const short8*)&B1l[base];
            #pragma unroll
            for (int nt = 0; nt < 4; ++nt) {
                acc2[mi][nt] = __builtin_amdgcn_mfma_f32_16x16x32_bf16(Ah, W2h[nt], acc2[mi][nt], 0, 0, 0);
                acc2[mi][nt] = __builtin_amdgcn_mfma_f32_16x16x32_bf16(Ah, W2l[nt], acc2[mi][nt], 0, 0, 0);
                acc2[mi][nt] = __builtin_amdgcn_mfma_f32_16x16x32_bf16(Al, W2h[nt], acc2[mi][nt], 0, 0, 0);
            }
        }
    }
    __syncthreads();   // B1 dead

    // ---- conv2 epilogue -> X2 (BN+ReLU+pool2, split bf16) ----
    {
        #pragma unroll
        for (int mi = 0; mi < 4; ++mi) {
            const int mt = wid*4 + mi;
            const int r0 = mt*8 + quad*2 + 1;
            #pragma unroll
            for (int nt = 0; nt < 4; ++nt) {
                const int co = nt*16 + mrow;
                const float sc = sc2[co], sh = sh2[co];
                floatx4 d = acc2[mi][nt];
                float v0 = fmaxf(0.f, fmaxf(d[0]*sc + sh, d[1]*sc + sh));
                float v1 = fmaxf(0.f, fmaxf(d[2]*sc + sh, d[3]*sc + sh));
                unsigned uh, ul;
                bf16_split_fast(v0, uh, ul);
                X2h[r0*72 + co] = (short)uh; X2l[r0*72 + co] = (short)ul;
                bf16_split_fast(v1, uh, ul);
                X2h[(r0+1)*72 + co] = (short)uh; X2l[(r0+1)*72 + co] = (short)ul;
            }
        }
        if (tid < 72) {
            X2h[tid] = 0; X2l[tid] = 0;
            X2h[129*72 + tid] = 0; X2l[129*72 + tid] = 0;
        }
    }
    __syncthreads();

    // ---- conv3 MFMA: M=128, N=128, K=64, 3 taps, 3-term.
    // Wave w: mt {(w&1)*4..+3} x nt {(w>>1)*4..+3}.
    floatx4 acc3[4][4] = {};
    const int mt0 = (wid & 1) * 4;
    const int ntb = (wid >> 1) * 4;
    for (int t = 0; t < 3; ++t) {
        for (int ks = 0; ks < 2; ++ks) {
            const int fb = (t*2 + ks) * 8;
            short8 W3h[4], W3l[4];
            #pragma unroll
            for (int n = 0; n < 4; ++n) {
                W3h[n] = *(const short8*)(Wf3 + (((fb + ntb + n)*2 + 0)*512 + lane*8));
                W3l[n] = *(const short8*)(Wf3 + (((fb + ntb + n)*2 + 1)*512 + lane*8));
            }
            #pragma unroll
            for (int mi = 0; mi < 4; ++mi) {
                const int base = ((mt0 + mi)*16 + mrow + t)*72 + ks*32 + kq;
                const short8 Ah = *(const short8*)&X2h[base];
                const short8 Al = *(const short8*)&X2l[base];
                #pragma unroll
                for (int n = 0; n < 4; ++n) {
                    acc3[mi][n] = __builtin_amdgcn_mfma_f32_16x16x32_bf16(Ah, W3h[n], acc3[mi][n], 0, 0, 0);
                    acc3[mi][n] = __builtin_amdgcn_mfma_f32_16x16x32_bf16(Ah, W3l[n], acc3[mi][n], 0, 0, 0);
                    acc3[mi][n] = __builtin_amdgcn_mfma_f32_16x16x32_bf16(Al, W3h[n], acc3[mi][n], 0, 0, 0);
                }
            }
        }
    }
    __syncthreads();   // X2 region reads done; tail arrays live in Aim region

    // ---- conv3 epilogue: BN+ReLU+pool2+mean, 2-wave partial reduction ----
    {
        float s[4] = {0.f, 0.f, 0.f, 0.f};
        #pragma unroll
        for (int n = 0; n < 4; ++n) {
            const int co = (ntb + n)*16 + mrow;
            const float sc = sc3[co], sh = sh3[co];
            #pragma unroll
            for (int mi = 0; mi < 4; ++mi) {
                floatx4 d = acc3[mi][n];
                s[n] += fmaxf(0.f, fmaxf(d[0]*sc + sh, d[1]*sc + sh));
                s[n] += fmaxf(0.f, fmaxf(d[2]*sc + sh, d[3]*sc + sh));
            }
        }
        #pragma unroll
        for (int n = 0; n < 4; ++n) {
            s[n] += __shfl_xor(s[n], 16);
            s[n] += __shfl_xor(s[n], 32);
        }
        if (lane < 16) {
            #pragma unroll
            for (int n = 0; n < 4; ++n)
                part[(wid & 1)*128 + (ntb + n)*16 + lane] = s[n];
        }
    }
    __syncthreads();
    if (tid < 128) featm[tid] = (part[tid] + part[128 + tid]) * (1.0f / 64.0f);
    __syncthreads();

    // ---- linear 128->128 + BN + ReLU ----
    if (tid < 128) {
        const float* wr = pwf + (size_t)tid * 128;
        float s = 0.f;
        #pragma unroll 4
        for (int i = 0; i < 128; i += 4) {
            float4 w4 = *(const float4*)(wr + i);
            s += w4.x*featm[i] + w4.y*featm[i+1] + w4.z*featm[i+2] + w4.w*featm[i+3];
        }
        s += pbf[tid];
        s = (s - pmf[tid]) * (pgf[tid] * rsqrtf(pvf[tid] + EPS_BN)) + pbef[tid];
        featr[tid] = fmaxf(s, 0.f);
    }
    __syncthreads();

    // ---- L2 normalize ----
    if (tid < 128) {
        float ss = 0.f;
        for (int i = 0; i < 128; ++i) ss += featr[i] * featr[i];
        float n = fmaxf(sqrtf(ss), 1e-12f);
        feat_out[(size_t)sid * 128 + tid] = featr[tid] / n;
    }
}

// ---------------------------------------------------------------------------
// Prototypes: block = (b*NWAY + w), 128 threads (r5 version, measured cheap)
// ---------------------------------------------------------------------------
__global__ __launch_bounds__(128) void proto_kernel(
    const float* __restrict__ feat_s, const int* __restrict__ s_lab,
    float* __restrict__ protos)
{
    const int b = blockIdx.x / NWAY;
    const int w = blockIdx.x % NWAY;
    const int f = threadIdx.x;
    const float* sf = feat_s + (size_t)b * NSHOTB * 128;
    const int* lab = s_lab + b * NSHOTB;
    float acc = 0.f;
    int cnt = 0;
    for (int s = 0; s < NSHOTB; ++s) {
        int lv = lab[s];
        if (lv == w) { acc += sf[s*128 + f]; cnt++; }
    }
    protos[(size_t)blockIdx.x * 128 + f] = acc / (float)cnt;
}

__global__ __launch_bounds__(256) void dist_kernel(
    const float* __restrict__ feat_q, const float* __restrict__ protos,
    float* __restrict__ out)
{
    int idx = blockIdx.x * 256 + threadIdx.x;
    if (idx >= 32 * NQB * NWAY) return;
    int b = idx / (NQB * NWAY);
    int r = idx - b * (NQB * NWAY);
    int q = r / NWAY;
    int w = r - q * NWAY;
    const float* qf = feat_q + (size_t)(b * NQB + q) * 128;
    const float* pp = protos + (size_t)(b * NWAY + w) * 128;
    float d2 = 0.f;
    #pragma unroll 4
    for (int i = 0; i < 128; ++i) { float d = qf[i] - pp[i]; d2 += d * d; }
    out[idx] = -sqrtf(fmaxf(d2, 0.f));
}

// ---------------------------------------------------------------------------
extern "C" void kernel_launch(void* const* d_in, const int* in_sizes, int n_in,
                              void* d_out, int out_size, void* d_ws, size_t ws_size,
                              hipStream_t stream) {
    const float* s_img = (const float*)d_in[0];
    const float* q_img = (const float*)d_in[1];
    const int*   s_lab = (const int*)d_in[2];
    const float* pw1  = (const float*)d_in[3];
    const float* pb1  = (const float*)d_in[4];
    const float* pg1  = (const float*)d_in[5];
    const float* pbe1 = (const float*)d_in[6];
    const float* pm1  = (const float*)d_in[7];
    const float* pv1  = (const float*)d_in[8];
    const float* pw2  = (const float*)d_in[9];
    const float* pb2  = (const float*)d_in[10];
    const float* pg2  = (const float*)d_in[11];
    const float* pbe2 = (const float*)d_in[12];
    const float* pm2  = (const float*)d_in[13];
    const float* pv2  = (const float*)d_in[14];
    const float* pw3  = (const float*)d_in[15];
    const float* pb3  = (const float*)d_in[16];
    const float* pg3  = (const float*)d_in[17];
    const float* pbe3 = (const float*)d_in[18];
    const float* pm3  = (const float*)d_in[19];
    const float* pv3  = (const float*)d_in[20];
    const float* pwf  = (const float*)d_in[21];
    const float* pbf  = (const float*)d_in[22];
    const float* pgf  = (const float*)d_in[23];
    const float* pbef = (const float*)d_in[24];
    const float* pmf  = (const float*)d_in[25];
    const float* pvf  = (const float*)d_in[26];

    const size_t feat_elems = (size_t)NSAMP * 128;      // fp32
    const size_t prot_elems = (size_t)32 * NWAY * 128;  // fp32
    float* feat   = (float*)d_ws;
    float* protos = feat + feat_elems;
    unsigned short* Wf1 = (unsigned short*)(protos + prot_elems);
    unsigned short* Wf2 = Wf1 + 2048;    // 4  frags x 512
    unsigned short* Wf3 = Wf2 + 12288;   // 24 frags x 512; W3 = 96 x 512
    float* out = (float*)d_out;

    prep_weights<<<124, 256, 0, stream>>>(pw1, pw2, pw3, Wf1, Wf2, Wf3);

    encoder_fused<<<NSAMP, 256, 0, stream>>>(
        s_img, q_img,
        Wf1, pb1, pg1, pbe1, pm1, pv1,
        pb2, pg2, pbe2, pm2, pv2, Wf2,
        pb3, pg3, pbe3, pm3, pv3, Wf3,
        pwf, pbf, pgf, pbef, pmf, pvf,
        feat);

    proto_kernel<<<32 * NWAY, 128, 0, stream>>>(feat, s_lab, protos);

    dist_kernel<<<(32 * NQB * NWAY + 255) / 256, 256, 0, stream>>>(
        feat + (size_t)NSUP * 128, protos, out);
}

// Round 9
// 481.590 us; speedup vs baseline: 1.5797x; 1.2984x over previous
//
#include <hip/hip_runtime.h>
#include <math.h>

#define EPS_BN 1e-5f

// Problem constants: B=32, NS=200, NQ=100, C=8, L=512, H=32, F=128, N_WAY=20
#define NSUP   6400
#define NQRY   3200
#define NSAMP  9600
#define NWAY   20
#define NSHOTB 200
#define NQB    100

using short8  = __attribute__((ext_vector_type(8))) short;
using floatx4 = __attribute__((ext_vector_type(4))) float;

// accurate split (prep only): RNE both halves
__device__ __forceinline__ void bf16_split_rn(float x, unsigned& uh, unsigned& ul) {
    unsigned u = __float_as_uint(x);
    uh = (u + 0x7FFFu + ((u >> 16) & 1u)) >> 16;
    float e = x - __uint_as_float(uh << 16);
    unsigned ue = __float_as_uint(e);
    ul = (ue + 0x7FFFu + ((ue >> 16) & 1u)) >> 16;
}
// fast split (hot path): RNE hi, truncated lo
__device__ __forceinline__ void bf16_split_fast(float x, unsigned& uh, unsigned& ul) {
    unsigned u = __float_as_uint(x);
    uh = (u + 0x7FFFu + ((u >> 16) & 1u)) >> 16;
    float e = x - __uint_as_float(uh << 16);
    ul = __float_as_uint(e) >> 16;
}

// ===========================================================================
// prep: W1 [32][8][3], W2 [64][32][3], W3 [128][64][3] -> MFMA B-fragment
// order, split hi/lo bf16 (layouts verified rounds 4-8).
//  W1: frag=nt*2+hl; co=nt*16+(lane&15), k=quad*8+j -> t=quad, ci=j; t==3 -> 0
// ===========================================================================
__global__ __launch_bounds__(256) void prep_weights(
    const float* __restrict__ w1, const float* __restrict__ w2,
    const float* __restrict__ w3, unsigned short* __restrict__ Wf1,
    unsigned short* __restrict__ Wf2, unsigned short* __restrict__ Wf3)
{
    int b = blockIdx.x;
    if (b < 24) {                         // W2: 24 frags x 512
        int e = b * 512 + threadIdx.x;
        #pragma unroll
        for (int r = 0; r < 2; ++r, e += 256) {
            int frag = e >> 9, off = e & 511;
            int lane = off >> 3, j = off & 7;
            int hl = frag & 1, f2 = frag >> 1;
            int nt = f2 & 3, t = f2 >> 2;
            int co = nt * 16 + (lane & 15);
            int ci = (lane >> 4) * 8 + j;
            float x = w2[(co * 32 + ci) * 3 + t];
            unsigned uh, ul; bf16_split_rn(x, uh, ul);
            Wf2[e] = (unsigned short)(hl ? ul : uh);
        }
    } else if (b < 120) {                 // W3: 96 frags x 512
        int e = (b - 24) * 512 + threadIdx.x;
        #pragma unroll
        for (int r = 0; r < 2; ++r, e += 256) {
            int frag = e >> 9, off = e & 511;
            int lane = off >> 3, j = off & 7;
            int hl = frag & 1, f2 = frag >> 1;
            int nt = f2 & 7, f3 = f2 >> 3;
            int ks = f3 & 1, t = f3 >> 1;
            int co = nt * 16 + (lane & 15);
            int ci = ks * 32 + (lane >> 4) * 8 + j;
            float x = w3[(co * 64 + ci) * 3 + t];
            unsigned uh, ul; bf16_split_rn(x, uh, ul);
            Wf3[e] = (unsigned short)(hl ? ul : uh);
        }
    } else {                              // W1: 4 frags x 512
        int e = (b - 120) * 512 + threadIdx.x;
        #pragma unroll
        for (int r = 0; r < 2; ++r, e += 256) {
            int frag = e >> 9, off = e & 511;
            int lane = off >> 3, j = off & 7;
            int hl = frag & 1, nt = frag >> 1;
            int co = nt * 16 + (lane & 15);
            int t  = lane >> 4;           // quad = tap (K = t*8+ci)
            float x = (t < 3) ? w1[(co * 8 + j) * 3 + t] : 0.f;
            unsigned uh, ul; bf16_split_rn(x, uh, ul);
            Wf1[e] = (unsigned short)(hl ? ul : uh);
        }
    }
}

// ===========================================================================
// Fused encoder, all-MFMA convs. Round-8 structure but conv1 reads its
// A-fragments DIRECTLY from a transposed input buffer Xt[row][ci] (row
// stride 8 shorts = 16 B): lane (mrow, quad) loads b128 at row
// mt*16+mrow+quad, since k=quad*8+j maps to (t=quad, ci=j) and the W1
// fragment is zero for t==3 (quad-3 reads are harmless in-bounds rows).
// No im2col replication, no per-chunk barriers: conv1 = 2 halves x
// (build Xt once, barrier, barrier-free MFMA sweep).
// ===========================================================================
__global__ __launch_bounds__(256, 3) void encoder_fused(
    const float* __restrict__ s_img, const float* __restrict__ q_img,
    const unsigned short* __restrict__ Wf1,
    const float* __restrict__ pb1, const float* __restrict__ pg1,
    const float* __restrict__ pbe1, const float* __restrict__ pm1,
    const float* __restrict__ pv1,
    const float* __restrict__ pb2, const float* __restrict__ pg2,
    const float* __restrict__ pbe2, const float* __restrict__ pm2,
    const float* __restrict__ pv2, const unsigned short* __restrict__ Wf2,
    const float* __restrict__ pb3, const float* __restrict__ pg3,
    const float* __restrict__ pbe3, const float* __restrict__ pm3,
    const float* __restrict__ pv3, const unsigned short* __restrict__ Wf3,
    const float* __restrict__ pwf, const float* __restrict__ pbf,
    const float* __restrict__ pgf, const float* __restrict__ pbef,
    const float* __restrict__ pmf, const float* __restrict__ pvf,
    float* __restrict__ feat_out)
{
    // U regions (time-multiplexed):
    //  conv1/conv2: B1h @0 (20640), B1l @20640 (20640),
    //               Xth @41280 (260 rows x 8 shorts = 4160), Xtl @45440 (4160)
    //  conv3:       X2h @0 (18720), X2l @18720 (18720)
    //  tail:        part @41280 (1024), featm @42304 (512), featr @42816 (512)
    __shared__ __align__(16) char U[49600];
    short* const B1h = (short*)U;
    short* const B1l = (short*)(U + 20640);
    short* const Xth = (short*)(U + 41280);
    short* const Xtl = (short*)(U + 45440);
    short* const X2h = (short*)U;
    short* const X2l = (short*)(U + 18720);
    float* const part  = (float*)(U + 41280);   // [2][128]
    float* const featm = (float*)(U + 42304);   // [128]
    float* const featr = (float*)(U + 42816);   // [128]
    __shared__ float sc1[32], sh1[32], sc2[64], sh2[64], sc3[128], sh3[128];

    const int tid  = threadIdx.x;
    const int sid  = blockIdx.x;
    const int lane = tid & 63;
    const int wid  = tid >> 6;
    const int mrow = lane & 15;
    const int quad = lane >> 4;
    const int kq   = quad * 8;

    const float* xin = (sid < NSUP) ? (s_img + (size_t)sid * 4096)
                                    : (q_img + (size_t)(sid - NSUP) * 4096);

    // ---- init: fold BN params, zero Xt tail rows + B1 halo rows ----
    if (tid < 32) {
        float s = pg1[tid] * rsqrtf(pv1[tid] + EPS_BN);
        sc1[tid] = s; sh1[tid] = (pb1[tid] - pm1[tid]) * s + pbe1[tid];
    } else if (tid < 96) {
        int c = tid - 32;
        float s = pg2[c] * rsqrtf(pv2[c] + EPS_BN);
        sc2[c] = s; sh2[c] = (pb2[c] - pm2[c]) * s + pbe2[c];
    } else if (tid < 224) {
        int c = tid - 96;
        float s = pg3[c] * rsqrtf(pv3[c] + EPS_BN);
        sc3[c] = s; sh3[c] = (pb3[c] - pm3[c]) * s + pbe3[c];
    }
    if (tid < 8) {   // Xt rows 258,259 (quad-3 overreach): zero, avoid NaN bits
        ((unsigned*)(Xth + 258*8))[tid] = 0;
        ((unsigned*)(Xtl + 258*8))[tid] = 0;
    }
    if (tid < 40) {  // B1 halo rows 0, 257 (epilogues never write them)
        B1h[tid] = 0; B1l[tid] = 0;
        B1h[257*40 + tid] = 0; B1l[257*40 + tid] = 0;
    }
    // preload conv1 W fragments (persist in VGPRs)
    short8 W1h[2], W1l[2];
    #pragma unroll
    for (int nt = 0; nt < 2; ++nt) {
        W1h[nt] = *(const short8*)(Wf1 + ((nt*2 + 0)*512 + lane*8));
        W1l[nt] = *(const short8*)(Wf1 + ((nt*2 + 1)*512 + lane*8));
    }

    // ---- conv1: 2 halves of 256 pre-pool rows ----
    for (int h = 0; h < 2; ++h) {
        // build Xt: row r holds X[*][l], l = h*256 + r - 1 (zero OOB).
        // b128 writes, stride 16 B -> conflict-free; global reads coalesced.
        for (int row = tid; row < 258; row += 256) {
            int l = h*256 + row - 1;
            short8 vh, vl;
            #pragma unroll
            for (int ci = 0; ci < 8; ++ci) {
                float x = (l >= 0 && l < 512) ? xin[ci*512 + l] : 0.f;
                unsigned uh, ul; bf16_split_fast(x, uh, ul);
                vh[ci] = (short)uh; vl[ci] = (short)ul;
            }
            *(short8*)&Xth[row*8] = vh;
            *(short8*)&Xtl[row*8] = vl;
        }
        __syncthreads();
        // MFMA sweep: wave owns mt_local {4w..4w+3}; A-frag = one b128/row
        #pragma unroll
        for (int mi = 0; mi < 4; ++mi) {
            const int mtl = wid*4 + mi;
            const int mt  = h*16 + mtl;
            const int row = mtl*16 + mrow + quad;
            const short8 Ah = *(const short8*)&Xth[row*8];
            const short8 Al = *(const short8*)&Xtl[row*8];
            floatx4 a1[2] = {};
            #pragma unroll
            for (int nt = 0; nt < 2; ++nt) {
                a1[nt] = __builtin_amdgcn_mfma_f32_16x16x32_bf16(Ah, W1h[nt], a1[nt], 0, 0, 0);
                a1[nt] = __builtin_amdgcn_mfma_f32_16x16x32_bf16(Ah, W1l[nt], a1[nt], 0, 0, 0);
                a1[nt] = __builtin_amdgcn_mfma_f32_16x16x32_bf16(Al, W1h[nt], a1[nt], 0, 0, 0);
                a1[nt] = __builtin_amdgcn_mfma_f32_16x16x32_bf16(Al, W1l[nt], a1[nt], 0, 0, 0);
            }
            // epilogue: BN+ReLU+pool2 -> B1 rows
            const int pl0 = mt*8 + quad*2 + 1;   // +1 halo
            #pragma unroll
            for (int nt = 0; nt < 2; ++nt) {
                const int co = nt*16 + mrow;
                const float sc = sc1[co], sh = sh1[co];
                floatx4 d = a1[nt];
                float v0 = fmaxf(0.f, fmaxf(d[0]*sc + sh, d[1]*sc + sh));
                float v1 = fmaxf(0.f, fmaxf(d[2]*sc + sh, d[3]*sc + sh));
                unsigned uh, ul;
                bf16_split_fast(v0, uh, ul);
                B1h[pl0*40 + co] = (short)uh; B1l[pl0*40 + co] = (short)ul;
                bf16_split_fast(v1, uh, ul);
                B1h[(pl0+1)*40 + co] = (short)uh; B1l[(pl0+1)*40 + co] = (short)ul;
            }
        }
        __syncthreads();   // protect Xt for next half / B1 complete for conv2
    }

    // ---- conv2 MFMA: M=256, N=64, K=32, 3 taps, 3-term.
    // Wave w owns mt {4w..4w+3} x ALL nt {0..3}.
    floatx4 acc2[4][4] = {};
    for (int t = 0; t < 3; ++t) {
        short8 W2h[4], W2l[4];
        #pragma unroll
        for (int nt = 0; nt < 4; ++nt) {
            W2h[nt] = *(const short8*)(Wf2 + (((t*4 + nt)*2 + 0)*512 + lane*8));
            W2l[nt] = *(const short8*)(Wf2 + (((t*4 + nt)*2 + 1)*512 + lane*8));
        }
        #pragma unroll
        for (int mi = 0; mi < 4; ++mi) {
            const int mt = wid*4 + mi;
            const int base = (mt*16 + mrow + t)*40 + kq;
            const short8 Ah = *(const short8*)&B1h[base];
            const short8 Al = *(const short8*)&B1l[base];
            #pragma unroll
            for (int nt = 0; nt < 4; ++nt) {
                acc2[mi][nt] = __builtin_amdgcn_mfma_f32_16x16x32_bf16(Ah, W2h[nt], acc2[mi][nt], 0, 0, 0);
                acc2[mi][nt] = __builtin_amdgcn_mfma_f32_16x16x32_bf16(Ah, W2l[nt], acc2[mi][nt], 0, 0, 0);
                acc2[mi][nt] = __builtin_amdgcn_mfma_f32_16x16x32_bf16(Al, W2h[nt], acc2[mi][nt], 0, 0, 0);
            }
        }
    }
    __syncthreads();   // B1 dead

    // ---- conv2 epilogue -> X2 (BN+ReLU+pool2, split bf16) ----
    {
        #pragma unroll
        for (int mi = 0; mi < 4; ++mi) {
            const int mt = wid*4 + mi;
            const int r0 = mt*8 + quad*2 + 1;
            #pragma unroll
            for (int nt = 0; nt < 4; ++nt) {
                const int co = nt*16 + mrow;
                const float sc = sc2[co], sh = sh2[co];
                floatx4 d = acc2[mi][nt];
                float v0 = fmaxf(0.f, fmaxf(d[0]*sc + sh, d[1]*sc + sh));
                float v1 = fmaxf(0.f, fmaxf(d[2]*sc + sh, d[3]*sc + sh));
                unsigned uh, ul;
                bf16_split_fast(v0, uh, ul);
                X2h[r0*72 + co] = (short)uh; X2l[r0*72 + co] = (short)ul;
                bf16_split_fast(v1, uh, ul);
                X2h[(r0+1)*72 + co] = (short)uh; X2l[(r0+1)*72 + co] = (short)ul;
            }
        }
        if (tid < 72) {
            X2h[tid] = 0; X2l[tid] = 0;
            X2h[129*72 + tid] = 0; X2l[129*72 + tid] = 0;
        }
    }
    __syncthreads();

    // ---- conv3 MFMA: M=128, N=128, K=64, 3 taps, 3-term.
    // Wave w: mt {(w&1)*4..+3} x nt {(w>>1)*4..+3}.
    floatx4 acc3[4][4] = {};
    const int mt0 = (wid & 1) * 4;
    const int ntb = (wid >> 1) * 4;
    for (int t = 0; t < 3; ++t) {
        for (int ks = 0; ks < 2; ++ks) {
            const int fb = (t*2 + ks) * 8;
            short8 W3h[4], W3l[4];
            #pragma unroll
            for (int n = 0; n < 4; ++n) {
                W3h[n] = *(const short8*)(Wf3 + (((fb + ntb + n)*2 + 0)*512 + lane*8));
                W3l[n] = *(const short8*)(Wf3 + (((fb + ntb + n)*2 + 1)*512 + lane*8));
            }
            #pragma unroll
            for (int mi = 0; mi < 4; ++mi) {
                const int base = ((mt0 + mi)*16 + mrow + t)*72 + ks*32 + kq;
                const short8 Ah = *(const short8*)&X2h[base];
                const short8 Al = *(const short8*)&X2l[base];
                #pragma unroll
                for (int n = 0; n < 4; ++n) {
                    acc3[mi][n] = __builtin_amdgcn_mfma_f32_16x16x32_bf16(Ah, W3h[n], acc3[mi][n], 0, 0, 0);
                    acc3[mi][n] = __builtin_amdgcn_mfma_f32_16x16x32_bf16(Ah, W3l[n], acc3[mi][n], 0, 0, 0);
                    acc3[mi][n] = __builtin_amdgcn_mfma_f32_16x16x32_bf16(Al, W3h[n], acc3[mi][n], 0, 0, 0);
                }
            }
        }
    }
    __syncthreads();   // X2 reads done; tail arrays live in Xt region

    // ---- conv3 epilogue: BN+ReLU+pool2+mean, 2-wave partial reduction ----
    {
        float s[4] = {0.f, 0.f, 0.f, 0.f};
        #pragma unroll
        for (int n = 0; n < 4; ++n) {
            const int co = (ntb + n)*16 + mrow;
            const float sc = sc3[co], sh = sh3[co];
            #pragma unroll
            for (int mi = 0; mi < 4; ++mi) {
                floatx4 d = acc3[mi][n];
                s[n] += fmaxf(0.f, fmaxf(d[0]*sc + sh, d[1]*sc + sh));
                s[n] += fmaxf(0.f, fmaxf(d[2]*sc + sh, d[3]*sc + sh));
            }
        }
        #pragma unroll
        for (int n = 0; n < 4; ++n) {
            s[n] += __shfl_xor(s[n], 16);
            s[n] += __shfl_xor(s[n], 32);
        }
        if (lane < 16) {
            #pragma unroll
            for (int n = 0; n < 4; ++n)
                part[(wid & 1)*128 + (ntb + n)*16 + lane] = s[n];
        }
    }
    __syncthreads();
    if (tid < 128) featm[tid] = (part[tid] + part[128 + tid]) * (1.0f / 64.0f);
    __syncthreads();

    // ---- linear 128->128 + BN + ReLU ----
    if (tid < 128) {
        const float* wr = pwf + (size_t)tid * 128;
        float s = 0.f;
        #pragma unroll 4
        for (int i = 0; i < 128; i += 4) {
            float4 w4 = *(const float4*)(wr + i);
            s += w4.x*featm[i] + w4.y*featm[i+1] + w4.z*featm[i+2] + w4.w*featm[i+3];
        }
        s += pbf[tid];
        s = (s - pmf[tid]) * (pgf[tid] * rsqrtf(pvf[tid] + EPS_BN)) + pbef[tid];
        featr[tid] = fmaxf(s, 0.f);
    }
    __syncthreads();

    // ---- L2 normalize ----
    if (tid < 128) {
        float ss = 0.f;
        for (int i = 0; i < 128; ++i) ss += featr[i] * featr[i];
        float n = fmaxf(sqrtf(ss), 1e-12f);
        feat_out[(size_t)sid * 128 + tid] = featr[tid] / n;
    }
}

// ---------------------------------------------------------------------------
__global__ __launch_bounds__(128) void proto_kernel(
    const float* __restrict__ feat_s, const int* __restrict__ s_lab,
    float* __restrict__ protos)
{
    const int b = blockIdx.x / NWAY;
    const int w = blockIdx.x % NWAY;
    const int f = threadIdx.x;
    const float* sf = feat_s + (size_t)b * NSHOTB * 128;
    const int* lab = s_lab + b * NSHOTB;
    float acc = 0.f;
    int cnt = 0;
    for (int s = 0; s < NSHOTB; ++s) {
        int lv = lab[s];
        if (lv == w) { acc += sf[s*128 + f]; cnt++; }
    }
    protos[(size_t)blockIdx.x * 128 + f] = acc / (float)cnt;
}

__global__ __launch_bounds__(256) void dist_kernel(
    const float* __restrict__ feat_q, const float* __restrict__ protos,
    float* __restrict__ out)
{
    int idx = blockIdx.x * 256 + threadIdx.x;
    if (idx >= 32 * NQB * NWAY) return;
    int b = idx / (NQB * NWAY);
    int r = idx - b * (NQB * NWAY);
    int q = r / NWAY;
    int w = r - q * NWAY;
    const float* qf = feat_q + (size_t)(b * NQB + q) * 128;
    const float* pp = protos + (size_t)(b * NWAY + w) * 128;
    float d2 = 0.f;
    #pragma unroll 4
    for (int i = 0; i < 128; ++i) { float d = qf[i] - pp[i]; d2 += d * d; }
    out[idx] = -sqrtf(fmaxf(d2, 0.f));
}

// ---------------------------------------------------------------------------
extern "C" void kernel_launch(void* const* d_in, const int* in_sizes, int n_in,
                              void* d_out, int out_size, void* d_ws, size_t ws_size,
                              hipStream_t stream) {
    const float* s_img = (const float*)d_in[0];
    const float* q_img = (const float*)d_in[1];
    const int*   s_lab = (const int*)d_in[2];
    const float* pw1  = (const float*)d_in[3];
    const float* pb1  = (const float*)d_in[4];
    const float* pg1  = (const float*)d_in[5];
    const float* pbe1 = (const float*)d_in[6];
    const float* pm1  = (const float*)d_in[7];
    const float* pv1  = (const float*)d_in[8];
    const float* pw2  = (const float*)d_in[9];
    const float* pb2  = (const float*)d_in[10];
    const float* pg2  = (const float*)d_in[11];
    const float* pbe2 = (const float*)d_in[12];
    const float* pm2  = (const float*)d_in[13];
    const float* pv2  = (const float*)d_in[14];
    const float* pw3  = (const float*)d_in[15];
    const float* pb3  = (const float*)d_in[16];
    const float* pg3  = (const float*)d_in[17];
    const float* pbe3 = (const float*)d_in[18];
    const float* pm3  = (const float*)d_in[19];
    const float* pv3  = (const float*)d_in[20];
    const float* pwf  = (const float*)d_in[21];
    const float* pbf  = (const float*)d_in[22];
    const float* pgf  = (const float*)d_in[23];
    const float* pbef = (const float*)d_in[24];
    const float* pmf  = (const float*)d_in[25];
    const float* pvf  = (const float*)d_in[26];

    const size_t feat_elems = (size_t)NSAMP * 128;      // fp32
    const size_t prot_elems = (size_t)32 * NWAY * 128;  // fp32
    float* feat   = (float*)d_ws;
    float* protos = feat + feat_elems;
    unsigned short* Wf1 = (unsigned short*)(protos + prot_elems);
    unsigned short* Wf2 = Wf1 + 2048;    // 4  frags x 512
    unsigned short* Wf3 = Wf2 + 12288;   // 24 frags x 512; W3 = 96 x 512
    float* out = (float*)d_out;

    prep_weights<<<124, 256, 0, stream>>>(pw1, pw2, pw3, Wf1, Wf2, Wf3);

    encoder_fused<<<NSAMP, 256, 0, stream>>>(
        s_img, q_img,
        Wf1, pb1, pg1, pbe1, pm1, pv1,
        pb2, pg2, pbe2, pm2, pv2, Wf2,
        pb3, pg3, pbe3, pm3, pv3, Wf3,
        pwf, pbf, pgf, pbef, pmf, pvf,
        feat);

    proto_kernel<<<32 * NWAY, 128, 0, stream>>>(feat, s_lab, protos);

    dist_kernel<<<(32 * NQB * NWAY + 255) / 256, 256, 0, stream>>>(
        feat + (size_t)NSUP * 128, protos, out);
}